// Round 10
// baseline (378.013 us; speedup 1.0000x reference)
//
#include <hip/hip_runtime.h>

#define N_NODES 100000
#define N_EDGES 1600000
#define HIDDEN  128
#define OUTF    64
#define TILE    1024
#define NTILES  ((N_NODES + TILE - 1) / TILE)   // 98
#define NREP    8

// ---------------- bf16 helpers (RTE) ----------------
__device__ __forceinline__ unsigned short f2bf(float f) {
    unsigned u = __float_as_uint(f);
    u += 0x7fffu + ((u >> 16) & 1u);
    return (unsigned short)(u >> 16);
}
// unpack packed pair of bf16 (lo = even feature)
__device__ __forceinline__ float2 bfp2f(unsigned p) {
    return make_float2(__uint_as_float(p << 16), __uint_as_float(p & 0xffff0000u));
}

// ---------------- zero ints ----------------
__global__ void zero_kernel(int4* p, int n4) {
    int i = blockIdx.x * blockDim.x + threadIdx.x;
    if (i < n4) p[i] = make_int4(0, 0, 0, 0);
}

// ---------------- count degrees into REPLICATED arrays; return = replica-local rank ----------------
__global__ void count_kernel(const int* __restrict__ ei,
                             int* __restrict__ cntR,
                             int* __restrict__ rank) {
    int* cnt = cntR + (blockIdx.x & (NREP - 1)) * N_NODES;
    int t  = blockIdx.x * blockDim.x + threadIdx.x;
    int e0 = t * 4;
    if (e0 + 3 < N_EDGES) {
        int4 r4 = *(const int4*)(ei + e0);
        int k0 = atomicAdd(&cnt[r4.x], 1);
        int k1 = atomicAdd(&cnt[r4.y], 1);
        int k2 = atomicAdd(&cnt[r4.z], 1);
        int k3 = atomicAdd(&cnt[r4.w], 1);
        *(int4*)(rank + e0) = make_int4(k0, k1, k2, k3);
    } else {
        for (int e = e0; e < N_EDGES; ++e) rank[e] = atomicAdd(&cnt[ei[e]], 1);
    }
}

// ---------------- scan stage 1: per-tile exclusive scan over summed replicas ----------------
__global__ __launch_bounds__(256) void scan_tiles_kernel(const int* __restrict__ cntR,
                                                         int* __restrict__ rowptr,
                                                         int* __restrict__ tileSum) {
    __shared__ int ps[256];
    int tid  = threadIdx.x;
    int base = blockIdx.x * TILE + tid * 4;
    int a0 = 0, a1 = 0, a2 = 0, a3 = 0;
    #pragma unroll
    for (int r = 0; r < NREP; ++r) {
        const int* c = cntR + r * N_NODES;
        if (base + 3 < N_NODES) {
            int4 v = *(const int4*)(c + base);
            a0 += v.x; a1 += v.y; a2 += v.z; a3 += v.w;
        } else {
            if (base + 0 < N_NODES) a0 += c[base + 0];
            if (base + 1 < N_NODES) a1 += c[base + 1];
            if (base + 2 < N_NODES) a2 += c[base + 2];
            if (base + 3 < N_NODES) a3 += c[base + 3];
        }
    }
    int s = a0 + a1 + a2 + a3;
    ps[tid] = s;
    __syncthreads();
    for (int off = 1; off < 256; off <<= 1) {
        int t = (tid >= off) ? ps[tid - off] : 0;
        __syncthreads();
        ps[tid] += t;
        __syncthreads();
    }
    int ex = ps[tid] - s;
    int e0 = ex, e1 = e0 + a0, e2 = e1 + a1, e3 = e2 + a2;
    if (base + 3 < N_NODES) {
        *(int4*)(rowptr + base) = make_int4(e0, e1, e2, e3);
    } else {
        if (base + 0 < N_NODES) rowptr[base + 0] = e0;
        if (base + 1 < N_NODES) rowptr[base + 1] = e1;
        if (base + 2 < N_NODES) rowptr[base + 2] = e2;
        if (base + 3 < N_NODES) rowptr[base + 3] = e3;
    }
    if (tid == 255) tileSum[blockIdx.x] = ps[255];
}

// ---------------- scan stage 2: scan tile sums ----------------
__global__ __launch_bounds__(128) void scan_sums_kernel(const int* __restrict__ tileSum,
                                                        int* __restrict__ tileOff,
                                                        int* __restrict__ rowptr) {
    __shared__ int ps[128];
    int tid = threadIdx.x;
    int v = (tid < NTILES) ? tileSum[tid] : 0;
    ps[tid] = v;
    __syncthreads();
    for (int off = 1; off < 128; off <<= 1) {
        int t = (tid >= off) ? ps[tid - off] : 0;
        __syncthreads();
        ps[tid] += t;
        __syncthreads();
    }
    if (tid < NTILES) tileOff[tid] = ps[tid] - v;
    if (tid == 127) rowptr[N_NODES] = ps[127];
}

// ---------------- scan stage 3: finalize rowptr, per-replica bases RO, dinv, rdinv ----------------
__global__ void finalize_kernel(const int* __restrict__ cntR,
                                const int* __restrict__ tileOff,
                                int* __restrict__ rowptr,
                                int* __restrict__ RO,
                                float* __restrict__ dinv,
                                float* __restrict__ rdinv) {
    int i = blockIdx.x * blockDim.x + threadIdx.x;
    if (i < N_NODES) {
        int run = rowptr[i] + tileOff[i / TILE];
        rowptr[i] = run;
        int total = 0;
        #pragma unroll
        for (int r = 0; r < NREP; ++r) {
            RO[r * N_NODES + i] = run;
            int c = cntR[r * N_NODES + i];
            run += c;
            total += c;
        }
        float d  = fmaxf((float)total, 1.0f);
        dinv[i]  = rsqrtf(d);
        rdinv[i] = sqrtf(d);
    }
}

// ---------------- fill CSR columns: no atomics; same grid as count so rep matches ----------------
__global__ void fill_kernel(const int* __restrict__ ei,
                            const int* __restrict__ RO,
                            const int* __restrict__ rank,
                            int* __restrict__ csr_col) {
    const int* ro = RO + (blockIdx.x & (NREP - 1)) * N_NODES;
    int t  = blockIdx.x * blockDim.x + threadIdx.x;
    int e0 = t * 4;
    if (e0 + 3 < N_EDGES) {
        int4 r4 = *(const int4*)(ei + e0);
        int4 c4 = *(const int4*)(ei + N_EDGES + e0);
        int4 k4 = *(const int4*)(rank + e0);
        csr_col[ro[r4.x] + k4.x] = c4.x;
        csr_col[ro[r4.y] + k4.y] = c4.y;
        csr_col[ro[r4.z] + k4.z] = c4.z;
        csr_col[ro[r4.w] + k4.w] = c4.w;
    } else {
        for (int e = e0; e < N_EDGES; ++e)
            csr_col[ro[ei[e]] + rank[e]] = ei[N_EDGES + e];
    }
}

// ---------------- transpose W [OUTF][HIDDEN] -> Wt [HIDDEN][OUTF] ----------------
__global__ void wtrans_kernel(const float* __restrict__ W, float* __restrict__ Wt) {
    int i = blockIdx.x * blockDim.x + threadIdx.x;
    if (i < HIDDEN * OUTF) {
        int o = i / HIDDEN, k = i % HIDDEN;
        Wt[k * OUTF + o] = W[i];
    }
}

// ---------------- gemm: z0(bf16) = dinv .* (x @ W^T) ----------------
#define GR    64
#define BK    32
#define HSP   36
#define WTP   68
__global__ __launch_bounds__(256) void gemm_kernel(const float* __restrict__ x,
                                                   const float* __restrict__ Wt,
                                                   const float* __restrict__ dinv,
                                                   unsigned short* __restrict__ z0) {
    __shared__ float hs[GR * HSP];
    __shared__ float wt[BK * WTP];
    int tid = threadIdx.x;
    int rowBase = blockIdx.x * GR;

    int o4 = (tid & 15) * 4;
    int rq = (tid >> 4) * 4;
    float4 a0 = {0,0,0,0}, a1 = {0,0,0,0}, a2 = {0,0,0,0}, a3 = {0,0,0,0};

    for (int kt = 0; kt < HIDDEN / BK; ++kt) {
        if (kt) __syncthreads();
        int kbase = kt * BK;
        #pragma unroll
        for (int t = 0; t < 2; ++t) {
            int f = tid + t * 256;
            int r = f >> 3, c4 = (f & 7) * 4;
            int row = rowBase + r;
            float4 v = (row < N_NODES) ? *(const float4*)(x + (size_t)row * HIDDEN + kbase + c4)
                                       : make_float4(0.f, 0.f, 0.f, 0.f);
            *(float4*)&hs[r * HSP + c4] = v;
        }
        #pragma unroll
        for (int t = 0; t < 2; ++t) {
            int f = tid + t * 256;
            int k = f >> 4, c4 = (f & 15) * 4;
            float4 v = *(const float4*)(Wt + (size_t)(kbase + k) * OUTF + c4);
            *(float4*)&wt[k * WTP + c4] = v;
        }
        __syncthreads();
        #pragma unroll 8
        for (int kk = 0; kk < BK; ++kk) {
            float4 wv = *(const float4*)&wt[kk * WTP + o4];
            float h0 = hs[(rq + 0) * HSP + kk];
            float h1 = hs[(rq + 1) * HSP + kk];
            float h2 = hs[(rq + 2) * HSP + kk];
            float h3 = hs[(rq + 3) * HSP + kk];
            a0.x += h0 * wv.x; a0.y += h0 * wv.y; a0.z += h0 * wv.z; a0.w += h0 * wv.w;
            a1.x += h1 * wv.x; a1.y += h1 * wv.y; a1.z += h1 * wv.z; a1.w += h1 * wv.w;
            a2.x += h2 * wv.x; a2.y += h2 * wv.y; a2.z += h2 * wv.z; a2.w += h2 * wv.w;
            a3.x += h3 * wv.x; a3.y += h3 * wv.y; a3.z += h3 * wv.z; a3.w += h3 * wv.w;
        }
    }
    int row = rowBase + rq;
    #pragma unroll
    for (int r = 0; r < 4; ++r) {
        if (row + r < N_NODES) {
            float d = dinv[row + r];
            float4 a = (r == 0) ? a0 : (r == 1) ? a1 : (r == 2) ? a2 : a3;
            ushort4 s = {f2bf(a.x * d), f2bf(a.y * d), f2bf(a.z * d), f2bf(a.w * d)};
            *(ushort4*)&z0[(size_t)(row + r) * OUTF + o4] = s;
        }
    }
}

// ---------------- pull on z: quarter-wave — 16 lanes/edge, 4 edges per gather instr ----------------
// zdst[n] = dinv[n]^2 * sum_c zsrc[c]
__global__ __launch_bounds__(256) void pull_kernel(const int* __restrict__ rowptr,
                                                   const int* __restrict__ csr_col,
                                                   const float* __restrict__ dinv,
                                                   const unsigned short* __restrict__ zsrc,
                                                   unsigned short* __restrict__ zdst) {
    int node = blockIdx.x * 4 + (threadIdx.x >> 6);
    int lane = threadIdx.x & 63;
    if (node >= N_NODES) return;
    int g  = lane >> 4;         // edge group 0..3
    int fb = (lane & 15) * 4;   // 4-feature base
    int s = rowptr[node];
    int e = rowptr[node + 1];
    float4 acc = {0.f, 0.f, 0.f, 0.f};
    int i = s;
    for (; i + 7 < e; i += 8) {
        int c0 = csr_col[i + g];          // coalesced: 4 consecutive dwords
        int c1 = csr_col[i + 4 + g];
        uint2 p0 = *(const uint2*)(zsrc + (size_t)c0 * OUTF + fb);
        uint2 p1 = *(const uint2*)(zsrc + (size_t)c1 * OUTF + fb);
        float2 u0 = bfp2f(p0.x), v0 = bfp2f(p0.y);
        float2 u1 = bfp2f(p1.x), v1 = bfp2f(p1.y);
        acc.x += u0.x + u1.x; acc.y += u0.y + u1.y;
        acc.z += v0.x + v1.x; acc.w += v0.y + v1.y;
    }
    for (; i < e; i += 4) {
        if (i + g < e) {
            int c = csr_col[i + g];
            uint2 p = *(const uint2*)(zsrc + (size_t)c * OUTF + fb);
            float2 u = bfp2f(p.x), v = bfp2f(p.y);
            acc.x += u.x; acc.y += u.y; acc.z += v.x; acc.w += v.y;
        }
    }
    acc.x += __shfl_xor(acc.x, 16); acc.y += __shfl_xor(acc.y, 16);
    acc.z += __shfl_xor(acc.z, 16); acc.w += __shfl_xor(acc.w, 16);
    acc.x += __shfl_xor(acc.x, 32); acc.y += __shfl_xor(acc.y, 32);
    acc.z += __shfl_xor(acc.z, 32); acc.w += __shfl_xor(acc.w, 32);
    if (lane < 16) {
        float dn = dinv[node];
        float zs = dn * dn;
        ushort4 o = {f2bf(acc.x * zs), f2bf(acc.y * zs), f2bf(acc.z * zs), f2bf(acc.w * zs)};
        *(ushort4*)(zdst + (size_t)node * OUTF + fb) = o;
    }
}

// ---------------- fused layer-3 pull + mean + bias (fp32 out), quarter-wave ----------------
__global__ __launch_bounds__(256) void pull_merge_kernel(const int* __restrict__ rowptr,
                                                         const int* __restrict__ csr_col,
                                                         const float* __restrict__ dinv,
                                                         const float* __restrict__ rdinv,
                                                         const unsigned short* __restrict__ z0,
                                                         const unsigned short* __restrict__ z1,
                                                         const unsigned short* __restrict__ z2,
                                                         const float* __restrict__ b,
                                                         float* __restrict__ out) {
    int node = blockIdx.x * 4 + (threadIdx.x >> 6);
    int lane = threadIdx.x & 63;
    if (node >= N_NODES) return;
    int g  = lane >> 4;
    int fb = (lane & 15) * 4;
    int s = rowptr[node];
    int e = rowptr[node + 1];
    float4 acc = {0.f, 0.f, 0.f, 0.f};
    int i = s;
    for (; i + 7 < e; i += 8) {
        int c0 = csr_col[i + g];
        int c1 = csr_col[i + 4 + g];
        uint2 p0 = *(const uint2*)(z2 + (size_t)c0 * OUTF + fb);
        uint2 p1 = *(const uint2*)(z2 + (size_t)c1 * OUTF + fb);
        float2 u0 = bfp2f(p0.x), v0 = bfp2f(p0.y);
        float2 u1 = bfp2f(p1.x), v1 = bfp2f(p1.y);
        acc.x += u0.x + u1.x; acc.y += u0.y + u1.y;
        acc.z += v0.x + v1.x; acc.w += v0.y + v1.y;
    }
    for (; i < e; i += 4) {
        if (i + g < e) {
            int c = csr_col[i + g];
            uint2 p = *(const uint2*)(z2 + (size_t)c * OUTF + fb);
            float2 u = bfp2f(p.x), v = bfp2f(p.y);
            acc.x += u.x; acc.y += u.y; acc.z += v.x; acc.w += v.y;
        }
    }
    acc.x += __shfl_xor(acc.x, 16); acc.y += __shfl_xor(acc.y, 16);
    acc.z += __shfl_xor(acc.z, 16); acc.w += __shfl_xor(acc.w, 16);
    acc.x += __shfl_xor(acc.x, 32); acc.y += __shfl_xor(acc.y, 32);
    acc.z += __shfl_xor(acc.z, 32); acc.w += __shfl_xor(acc.w, 32);
    if (lane < 16) {
        size_t idx = (size_t)node * OUTF + fb;
        float rd = rdinv[node];
        float dn = dinv[node];
        uint2 q0 = *(const uint2*)(z0 + idx);
        uint2 q1 = *(const uint2*)(z1 + idx);
        uint2 q2 = *(const uint2*)(z2 + idx);
        float2 s0a = bfp2f(q0.x), s0b = bfp2f(q0.y);
        float2 s1a = bfp2f(q1.x), s1b = bfp2f(q1.y);
        float2 s2a = bfp2f(q2.x), s2b = bfp2f(q2.y);
        float4 bv = *(const float4*)(b + fb);
        float4 r;
        r.x = 0.25f * ((s0a.x + s1a.x + s2a.x) * rd + dn * acc.x) + bv.x;
        r.y = 0.25f * ((s0a.y + s1a.y + s2a.y) * rd + dn * acc.y) + bv.y;
        r.z = 0.25f * ((s0b.x + s1b.x + s2b.x) * rd + dn * acc.z) + bv.z;
        r.w = 0.25f * ((s0b.y + s1b.y + s2b.y) * rd + dn * acc.w) + bv.w;
        *(float4*)(out + idx) = r;
    }
}

extern "C" void kernel_launch(void* const* d_in, const int* in_sizes, int n_in,
                              void* d_out, int out_size, void* d_ws, size_t ws_size,
                              hipStream_t stream) {
    const float* x  = (const float*)d_in[0];
    const int*   ei = (const int*)d_in[1];     // int32, [2, E] flat
    const float* W  = (const float*)d_in[2];
    const float* b  = (const float*)d_in[3];
    float*       out = (float*)d_out;

    // workspace layout
    unsigned short* z0 = (unsigned short*)d_ws;               // N*64 bf16
    unsigned short* z1 = z0 + (size_t)N_NODES * OUTF;         // N*64 bf16
    unsigned short* z2 = z1 + (size_t)N_NODES * OUTF;         // N*64 bf16
    float* Wt      = (float*)(z2 + (size_t)N_NODES * OUTF);   // 8192 f32
    int*   csrcol  = (int*)(Wt + HIDDEN * OUTF);              // E
    int*   rank    = csrcol + N_EDGES;                        // E
    int*   rowptr  = rank + N_EDGES;                          // N+1
    int*   cntR    = rowptr + (N_NODES + 1);                  // NREP*N
    int*   RO      = cntR + NREP * N_NODES;                   // NREP*N
    float* dinv    = (float*)(RO + NREP * N_NODES);           // N
    float* rdinv   = dinv + N_NODES;                          // N
    int*   tileSum = (int*)(rdinv + N_NODES);                 // NTILES
    int*   tileOff = tileSum + NTILES;                        // NTILES

    const int BLK = 256;
    const int edge4Blocks = (N_EDGES / 4 + BLK - 1) / BLK;  // 1563
    const int nodeBlocks  = (N_NODES + BLK - 1) / BLK;
    const int cntZero4    = (NREP * N_NODES / 4 + BLK - 1) / BLK;
    const int pullBlocks  = (N_NODES + 3) / 4;
    const int gemmBlocks  = (N_NODES + GR - 1) / GR;        // 1563

    // ---- CSR build (replicated counts) ----
    zero_kernel<<<cntZero4, BLK, 0, stream>>>((int4*)cntR, NREP * N_NODES / 4);
    count_kernel<<<edge4Blocks, BLK, 0, stream>>>(ei, cntR, rank);
    scan_tiles_kernel<<<NTILES, BLK, 0, stream>>>(cntR, rowptr, tileSum);
    scan_sums_kernel<<<1, 128, 0, stream>>>(tileSum, tileOff, rowptr);
    finalize_kernel<<<nodeBlocks, BLK, 0, stream>>>(cntR, tileOff, rowptr, RO, dinv, rdinv);
    fill_kernel<<<edge4Blocks, BLK, 0, stream>>>(ei, RO, rank, csrcol);

    // ---- project once, propagate z in bf16, fuse final layer with merge ----
    wtrans_kernel<<<(HIDDEN * OUTF + BLK - 1) / BLK, BLK, 0, stream>>>(W, Wt);
    gemm_kernel<<<gemmBlocks, BLK, 0, stream>>>(x, Wt, dinv, z0);
    pull_kernel<<<pullBlocks, BLK, 0, stream>>>(rowptr, csrcol, dinv, z0, z1);
    pull_kernel<<<pullBlocks, BLK, 0, stream>>>(rowptr, csrcol, dinv, z1, z2);
    pull_merge_kernel<<<pullBlocks, BLK, 0, stream>>>(rowptr, csrcol, dinv, rdinv,
                                                      z0, z1, z2, b, out);
}